// Round 1
// 89.492 us; speedup vs baseline: 1.0100x; 1.0100x over previous
//
#include <hip/hip_runtime.h>

#define NQ 14
#define DIM 16384
#define OUT_N 1000
#define PRUNED 2048   // amps kept after S1 (e bits 13..11 == 111)

using v2f = __attribute__((ext_vector_type(2))) float;

__host__ __device__ constexpr int WI(int l, int i, int k) {
    return 14 + (l * 13 + i) * 2 + k;  // weights[l,i,k] slot after 14 bias slots
}

// LDS xor-swizzle for a 2048-float buffer: every access pattern used below
// is <=2-way bank aliased (free per m136).
__device__ __forceinline__ int swzB(int a) { return a ^ ((a >> 5) & 31); }

// RY on element-bit B of a tile of NP float2 pairs. B>=1 -> packed fp32.
template<int B, int NP>
__device__ __forceinline__ void ry(v2f* x, float c, float s) {
    if constexpr (B == 0) {
#pragma unroll
        for (int p = 0; p < NP; ++p) {
            float a0 = x[p].x, a1 = x[p].y;
            x[p].x = c * a0 - s * a1;
            x[p].y = s * a0 + c * a1;
        }
    } else {
        constexpr int pb = B - 1;
#pragma unroll
        for (int m = 0; m < NP / 2; ++m) {
            int p0 = ((m >> pb) << (pb + 1)) | (m & ((1 << pb) - 1));
            int p1 = p0 | (1 << pb);
            v2f lo = x[p0], hi = x[p1];
            x[p0] = lo * c - hi * s;
            x[p1] = hi * c + lo * s;
        }
    }
}

// CZ: negate elements with element-bits BH and BL both set.
template<int BH, int BL, int NP>
__device__ __forceinline__ void cz(v2f* x) {
    static_assert(BH > BL, "");
    if constexpr (BL >= 1) {
#pragma unroll
        for (int p = 0; p < NP; ++p)
            if (((p >> (BH - 1)) & 1) && ((p >> (BL - 1)) & 1)) x[p] = -x[p];
    } else {
#pragma unroll
        for (int p = 0; p < NP; ++p)
            if ((p >> (BH - 1)) & 1) x[p].y = -x[p].y;
    }
}

#define BLK(BH, I0, I1, NP)                                       \
    cz<BH, BH - 1, NP>(x);                                        \
    { float2 cc = csl[I0]; ry<BH, NP>(x, cc.x, cc.y); }           \
    { float2 cd = csl[I1]; ry<BH - 1, NP>(x, cd.x, cd.y); }

// ---------------------------------------------------------------------------
// Same dep-DAG-verified gate schedule as round-2 kernel (S1 + U1..U5).
// NEW mapping (this round): one 512-thread block = TWO batch rows.
//   waves 0-3 (t<256)  : S1 for row 2*blk+0  -> LDS buffer 0
//   waves 4-7 (t>=256) : S1 for row 2*blk+1  -> LDS buffer 1
//   tail: wave 0 (SIMD0) finishes buffer 0, wave 1 (SIMD1) finishes buffer 1
// This removes the old structure's tail serialization (both blocks' wave-0
// tails stacking on SIMD0) -- the two tails now run on different SIMDs.
// ---------------------------------------------------------------------------
__global__ __launch_bounds__(512, 2)
void qnn_fused3(const float* __restrict__ in, const float* __restrict__ wts,
                const float* __restrict__ bias, float* __restrict__ out,
                int nrows) {
    __shared__ float lds[2 * PRUNED];   // two 8 KB swizzled pruned-state buffers
    __shared__ float2 csl[66];
    __shared__ float red[8];

    const int t = threadIdx.x;
    const int half = t >> 8;            // which row this thread's S1 serves
    const int tt = t & 255;             // 256-thread index within the row
    const int brow = blockIdx.x * 2 + half;
    const int b = (brow < nrows) ? brow : (nrows - 1);   // clamp (odd-nb safety)

    // per-block cos/sin of the 66 angles (same for both rows)
    if (t < 66) {
        float th = (t < NQ) ? bias[t] : wts[t - NQ];
        csl[t] = make_float2(cosf(0.5f * th), sinf(0.5f * th));
    }

    // ---- load, layout e = l<<8 | tt: per-wave fully coalesced dword loads
    const float* __restrict__ xin = in + (size_t)b * DIM;
    v2f x[32];
#pragma unroll
    for (int p = 0; p < 32; ++p) {
        x[p].x = xin[((2 * p) << 8) | tt];
        x[p].y = xin[((2 * p + 1) << 8) | tt];
    }

    // ---- sum of squares -> per-row scale (4 waves per row)
    float pp = 0.f;
#pragma unroll
    for (int p = 0; p < 32; ++p) pp = fmaf(x[p].x, x[p].x, fmaf(x[p].y, x[p].y, pp));
#pragma unroll
    for (int d = 32; d; d >>= 1) pp += __shfl_xor(pp, d);
    if ((t & 63) == 0) red[t >> 6] = pp;
    __syncthreads();                      // also publishes csl
    const float scale = 1.0f / sqrtf(red[4 * half + 0] + red[4 * half + 1] +
                                     red[4 * half + 2] + red[4 * half + 3]);

    // ---- S1: q0->bit5 ... q5->bit0 of l
    { float2 cc;
      cc = csl[0]; ry<5, 32>(x, cc.x, cc.y);
      cc = csl[1]; ry<4, 32>(x, cc.x, cc.y);
      cc = csl[2]; ry<3, 32>(x, cc.x, cc.y);
      cc = csl[3]; ry<2, 32>(x, cc.x, cc.y);
      cc = csl[4]; ry<1, 32>(x, cc.x, cc.y);
      cc = csl[5]; ry<0, 32>(x, cc.x, cc.y); }
    BLK(5, WI(0,0,0), WI(0,0,1), 32)   // B(0,0): q0,q1
    BLK(3, WI(0,2,0), WI(0,2,1), 32)   // B(0,2): q2,q3
    BLK(1, WI(0,4,0), WI(0,4,1), 32)   // B(0,4): q4,q5
    BLK(4, WI(0,1,0), WI(0,1,1), 32)   // B(0,1): q1,q2
    BLK(2, WI(0,3,0), WI(0,3,1), 32)   // B(0,3): q3,q4
    BLK(5, WI(1,0,0), WI(1,0,1), 32)   // B(1,0): q0,q1
    BLK(3, WI(1,2,0), WI(1,2,1), 32)   // B(1,2): q2,q3
    BLK(4, WI(1,1,0), WI(1,1,1), 32)   // B(1,1): q1,q2

    // ---- prune: keep l in [56,64) -> a = (l-56)<<8 | tt, scaled, into own buf
    {
        float* __restrict__ pb = lds + half * PRUNED;
#pragma unroll
        for (int p = 28; p < 32; ++p) {
            pb[swzB(((2 * p - 56) << 8) | tt)] = x[p].x * scale;
            pb[swzB(((2 * p - 55) << 8) | tt)] = x[p].y * scale;
        }
    }
    __syncthreads();

    // ---- waves 0 and 1 finish the two pruned 2048-amp states in parallel
    if (t < 128) {
        const int s = t & 63;
        float* __restrict__ buf = lds + (t >> 6) * PRUNED;
#pragma unroll
        for (int l = 0; l < 32; ++l) {           // gather L1: a = s<<5 | l
            float v = buf[swzB((s << 5) | l)];
            if (l & 1) x[l >> 1].y = v; else x[l >> 1].x = v;
        }
        // U1: q9->4 q10->3 q11->2 q12->1 q13->0
        { float2 cc;
          cc = csl[9];  ry<4, 16>(x, cc.x, cc.y);
          cc = csl[10]; ry<3, 16>(x, cc.x, cc.y);
          cc = csl[11]; ry<2, 16>(x, cc.x, cc.y);
          cc = csl[12]; ry<1, 16>(x, cc.x, cc.y);
          cc = csl[13]; ry<0, 16>(x, cc.x, cc.y); }
        BLK(3, WI(0,10,0), WI(0,10,1), 16)   // B(0,10): q10,q11
        BLK(1, WI(0,12,0), WI(0,12,1), 16)   // B(0,12): q12,q13
        BLK(2, WI(0,11,0), WI(0,11,1), 16)   // B(0,11): q11,q12
        BLK(1, WI(1,12,0), WI(1,12,1), 16)   // B(1,12): q12,q13
#pragma unroll
        for (int l = 0; l < 32; ++l)             // X1 write L1
            buf[swzB((s << 5) | l)] = (l & 1) ? x[l >> 1].y : x[l >> 1].x;
    }
    __syncthreads();
    if (t < 128) {
        const int s = t & 63;
        float* __restrict__ buf = lds + (t >> 6) * PRUNED;
#pragma unroll
        for (int l = 0; l < 32; ++l) {           // read L2
            float v = buf[swzB(((s >> 4) << 9) | (l << 4) | (s & 15))];
            if (l & 1) x[l >> 1].y = v; else x[l >> 1].x = v;
        }
        // U2: q5->4 q6->3 q7->2 q8->1 q9->0
        { float2 cc;
          cc = csl[6]; ry<3, 16>(x, cc.x, cc.y);
          cc = csl[7]; ry<2, 16>(x, cc.x, cc.y);
          cc = csl[8]; ry<1, 16>(x, cc.x, cc.y); }
        BLK(3, WI(0,6,0), WI(0,6,1), 16)   // B(0,6): q6,q7
        BLK(1, WI(0,8,0), WI(0,8,1), 16)   // B(0,8): q8,q9
        BLK(4, WI(0,5,0), WI(0,5,1), 16)   // B(0,5): q5,q6
        BLK(2, WI(0,7,0), WI(0,7,1), 16)   // B(0,7): q7,q8
        BLK(3, WI(1,6,0), WI(1,6,1), 16)   // B(1,6): q6,q7
#pragma unroll
        for (int l = 0; l < 32; ++l)             // X2 write L2
            buf[swzB(((s >> 4) << 9) | (l << 4) | (s & 15))] =
                (l & 1) ? x[l >> 1].y : x[l >> 1].x;
    }
    __syncthreads();
    if (t < 128) {
        const int s = t & 63;
        float* __restrict__ buf = lds + (t >> 6) * PRUNED;
#pragma unroll
        for (int l = 0; l < 32; ++l) {           // read L3
            float v = buf[swzB(((s >> 2) << 7) | (l << 2) | (s & 3))];
            if (l & 1) x[l >> 1].y = v; else x[l >> 1].x = v;
        }
        // U3: q7->4 q8->3 q9->2 q10->1 q11->0
        BLK(2, WI(0,9,0),  WI(0,9,1),  16)   // B(0,9):  q9,q10
        BLK(3, WI(1,8,0),  WI(1,8,1),  16)   // B(1,8):  q8,q9
        BLK(1, WI(1,10,0), WI(1,10,1), 16)   // B(1,10): q10,q11
        BLK(4, WI(1,7,0),  WI(1,7,1),  16)   // B(1,7):  q7,q8
        BLK(2, WI(1,9,0),  WI(1,9,1),  16)   // B(1,9):  q9,q10
#pragma unroll
        for (int l = 0; l < 32; ++l)             // X3 write L3
            buf[swzB(((s >> 2) << 7) | (l << 2) | (s & 3))] =
                (l & 1) ? x[l >> 1].y : x[l >> 1].x;
    }
    __syncthreads();
    if (t < 128) {
        const int s = t & 63;
        float* __restrict__ buf = lds + (t >> 6) * PRUNED;
#pragma unroll
        for (int l = 0; l < 32; ++l) {           // read L4: a = l<<6 | s
            float v = buf[swzB((l << 6) | s)];
            if (l & 1) x[l >> 1].y = v; else x[l >> 1].x = v;
        }
        // U4: q3->4 q4->3 q5->2 q6->1 q7->0
        BLK(3, WI(1,4,0), WI(1,4,1), 16)   // B(1,4): q4,q5
        BLK(4, WI(1,3,0), WI(1,3,1), 16)   // B(1,3): q3,q4
        BLK(2, WI(1,5,0), WI(1,5,1), 16)   // B(1,5): q5,q6
#pragma unroll
        for (int l = 0; l < 32; ++l)             // X4 write L4
            buf[swzB((l << 6) | s)] = (l & 1) ? x[l >> 1].y : x[l >> 1].x;
    }
    __syncthreads();
    if (t < 128) {
        const int s = t & 63;
        const int w = t >> 6;
        float* __restrict__ buf = lds + w * PRUNED;
#pragma unroll
        for (int l = 0; l < 32; ++l) {           // read L1
            float v = buf[swzB((s << 5) | l)];
            if (l & 1) x[l >> 1].y = v; else x[l >> 1].x = v;
        }
        // U5: B(1,11): q11->2, q12->1
        BLK(2, WI(1,11,0), WI(1,11,1), 16)

        // output: e = 14336 + a, j = a - 1048 for a = s*32 + l in [1048,2048)
        const int rb = blockIdx.x * 2 + w;
        if (s >= 32 && rb < nrows) {
            float* __restrict__ orow = out + (size_t)rb * OUT_N;
            const int base = s * 32 - 1048;
#pragma unroll
            for (int l = 0; l < 32; ++l) {
                int j = base + l;
                float v = (l & 1) ? x[l >> 1].y : x[l >> 1].x;
                if (j >= 0) orow[j] = v * v;
            }
        }
    }
}

extern "C" void kernel_launch(void* const* d_in, const int* in_sizes, int n_in,
                              void* d_out, int out_size, void* d_ws, size_t ws_size,
                              hipStream_t stream) {
    const float* in   = (const float*)d_in[0];
    const float* wts  = (const float*)d_in[1];
    const float* bias = (const float*)d_in[2];
    float* out = (float*)d_out;

    const int nb = in_sizes[0] / DIM;        // 512 batch rows
    const int grid = (nb + 1) / 2;           // 2 rows per 512-thread block
    qnn_fused3<<<grid, 512, 0, stream>>>(in, wts, bias, out, nb);
}